// Round 7
// baseline (79.268 us; speedup 1.0000x reference)
//
#include <hip/hip_runtime.h>
#include <math.h>

// LogPolar resample: data (32,3,512,512) f32 -> out (32,3,512,512) f32.
//
// R7 structure:
//  1) table_kernel (2 blocks): rad=exp(j*max_r/512) (j-only), cos/sin(ang(i))
//     (i-only) -> 3*512 floats in d_ws. Correctly-rounded f32 via f64 libm,
//     bit-identical to the chain validated in R2-R6 (trunc/mask decisions are
//     discontinuous -> must match np reference exactly).
//  2) resample_kernel (98304 blocks = 393k waves, PPB=1, NG=96): rebuilds X,Y
//     from tables with native f32 ops (__fmul_rn/__fadd_rn == "exact op,
//     round once" -> bit-identical X,Y). f32 weights (error ~1e-7 << 6.5e-2
//     threshold). g = blockIdx % 96; since 96 % 8 == 0, blockIdx % 8 == g % 8
//     -> each XCD owns 12 planes (keeps per-XCD L2 gather fill ~12 MB total
//     instead of 8x L3 re-fetch).
//
// Ladder: R2 210 -> R3 186 -> R4 164 -> R6 98.7 (profiled); graph 146->63.
// Wave count 4k->131k tracked near-linearly; occupancy 73%, VALU 12%, HBM 19%
// at R6 -> latency hiding still binding -> push waves 3x (PPB 3->1).
// R5 anti-lesson: float4 gather merge regressed (L1 return-byte cost).

#define HW (512 * 512)
#define NPIX (512 * 512)
#define PLANES 96
#define PPB 1   // planes per resample block
#define NG 96   // plane groups (PLANES/PPB)

// ---------------- table kernel: 512 entries of rad/cos/sin ----------------
__global__ __launch_bounds__(256) void table_kernel(float* __restrict__ radT,
                                                    float* __restrict__ cT,
                                                    float* __restrict__ sT) {
  const int t = blockIdx.x * 256 + threadIdx.x;  // 0..511

  // max_r = log(sqrt(512^2+512^2)/2 * 700), all in f32 steps (CR via f64)
  const float sq_f = (float)sqrt(524288.0);             // f32 sqrt (CR)
  const float half_f = sq_f * 0.5f;                     // exact
  const float prod_f = (float)((double)half_f * 700.0); // f32 mul emulated
  const float maxr_f = (float)log((double)prod_f);      // f32 log (CR)

  // rad = exp(t * max_r / 512) in f32 steps
  const float t1 = (float)((double)(float)t * (double)maxr_f); // f32 mul
  const float tt = t1 * (1.0f / 512.0f);                       // exact (pow2)
  radT[t] = (float)exp((double)tt);                            // f32 exp (CR)

  // ang = t * 2.0 * f32(pi) / 512 in f32 steps
  const float two_i = (float)(2 * t);  // exact
  const float ang1 = (float)((double)two_i * (double)(float)M_PI); // f32 mul
  const float ang = ang1 * (1.0f / 512.0f);                        // exact
  cT[t] = (float)cos((double)ang);  // f32 cos (CR)
  sT[t] = (float)sin((double)ang);  // f32 sin (CR)
}

// ---------------- resample kernel ----------------
__global__ __launch_bounds__(256) void resample_kernel(
    const float* __restrict__ in, float* __restrict__ out,
    const float* __restrict__ radT, const float* __restrict__ cT,
    const float* __restrict__ sT) {
  // g = blockIdx % NG (magic-mul, scalar); blockIdx % 8 == g % 8 -> XCD owns
  // the plane set {g : g % 8 == xcd} (12 planes).
  const int pixblock = (int)(blockIdx.x / NG);
  const int g = (int)blockIdx.x - pixblock * NG;  // plane index (PPB=1)
  const int pix = pixblock * 256 + (int)threadIdx.x;
  const int i = pix >> 9;   // theta bin (block-uniform)
  const int j = pix & 511;  // radius bin

  const float rad = radT[j];
  const float c = cT[i];
  const float s = sT[i];

  // Native f32 ops == "exact in f64, round once" -> X,Y bit-identical to the
  // validated chain; all trunc/mask decisions follow from X,Y alone.
  const float X = __fadd_rn(256.0f, __fmul_rn(rad, c));
  const float Y = __fsub_rn(256.0f, __fmul_rn(rad, s));

  float* op = out + (size_t)g * HW + pix;

  const bool inb = (X >= 0.0f) && (X < 512.0f) && (Y >= 0.0f) && (Y < 512.0f);
  if (!inb) {
    __builtin_nontemporal_store(0.0f, op);
    return;
  }

  // corner indices (decisions from bit-exact X,Y) + f32 weights
  const int yd = (int)Y;  // trunc == floor for Y in [0,512)
  const int xd = (int)X;
  const int yu = min(yd + 1, 511);
  const int xu = min(xd + 1, 511);
  const float fyd = (Y - (float)yd) * (Y - (float)yd);
  const float fyu = (Y - (float)yu) * (Y - (float)yu);
  const float fxd = (X - (float)xd) * (X - (float)xd);
  const float fxu = (X - (float)xu) * (X - (float)xu);
  const float dd = fyd + fxd;
  const float du = fyd + fxu;
  const float ud = fyu + fxd;
  const float uu = fyu + fxu;
  const float inv = 1.0f / (dd + du + ud + uu);
  const float wdd = dd * inv;
  const float wdu = du * inv;
  const float wud = ud * inv;
  const float wuu = uu * inv;

  const int i00 = yd * 512 + xd;
  const int i01 = yd * 512 + xu;
  const int i10 = yu * 512 + xd;
  const int i11 = yu * 512 + xu;

  const float* ip = in + (size_t)g * HW;
  const float v =
      wdd * ip[i00] + wdu * ip[i01] + wud * ip[i10] + wuu * ip[i11];
  __builtin_nontemporal_store(v, op);
}

// ---------------- fallback: proven R2 monolithic kernel ----------------
__global__ __launch_bounds__(256) void logpolar_mono(
    const float* __restrict__ in, float* __restrict__ out) {
  const int pix = blockIdx.x * 256 + threadIdx.x;
  const int i = pix >> 9;
  const int j = pix & 511;

  const float sq_f = (float)sqrt(524288.0);
  const float half_f = sq_f * 0.5f;
  const float prod_f = (float)((double)half_f * 700.0);
  const float maxr_f = (float)log((double)prod_f);
  const float t1 = (float)((double)(float)j * (double)maxr_f);
  const float t = t1 * (1.0f / 512.0f);
  const float rad_f = (float)exp((double)t);
  const float two_i = (float)(2 * i);
  const float ang1 = (float)((double)two_i * (double)(float)M_PI);
  const float ang = ang1 * (1.0f / 512.0f);
  const float c_f = (float)cos((double)ang);
  const float s_f = (float)sin((double)ang);
  const float X0 = (float)((double)rad_f * (double)c_f);
  const float Y0 = (float)((double)rad_f * (double)s_f);
  const float X = (float)(256.0 + (double)X0);
  const float Y = (float)(256.0 - (double)Y0);

  const bool inb = (X >= 0.0f) && (X < 512.0f) && (Y >= 0.0f) && (Y < 512.0f);

  float wdd = 0.f, wdu = 0.f, wud = 0.f, wuu = 0.f;
  int idd = 0, idu = 0, iud = 0, iuu = 0;
  if (inb) {
    const int yd = (int)Y;
    const int xd = (int)X;
    const int yu = min(yd + 1, 511);
    const int xu = min(xd + 1, 511);
    const double Xd = (double)X, Yd = (double)Y;
    const double dyd = (Yd - (double)yd) * (Yd - (double)yd);
    const double dyu = (Yd - (double)yu) * (Yd - (double)yu);
    const double dxd = (Xd - (double)xd) * (Xd - (double)xd);
    const double dxu = (Xd - (double)xu) * (Xd - (double)xu);
    const double dd = dyd + dxd;
    const double du = dyd + dxu;
    const double ud = dyu + dxd;
    const double uu = dyu + dxu;
    const double inv = 1.0 / (dd + du + ud + uu);
    wdd = (float)(dd * inv);
    wdu = (float)(du * inv);
    wud = (float)(ud * inv);
    wuu = (float)(uu * inv);
    idd = yd * 512 + xd;
    idu = yd * 512 + xu;
    iud = yu * 512 + xd;
    iuu = yu * 512 + xu;
  }

  const float* __restrict__ ip = in;
  float* __restrict__ op = out + pix;
#pragma unroll 4
  for (int p = 0; p < PLANES; ++p) {
    float v = 0.0f;
    if (inb) {
      v = wdd * ip[idd] + wdu * ip[idu] + wud * ip[iud] + wuu * ip[iuu];
    }
    *op = v;
    ip += HW;
    op += HW;
  }
}

extern "C" void kernel_launch(void* const* d_in, const int* in_sizes, int n_in,
                              void* d_out, int out_size, void* d_ws,
                              size_t ws_size, hipStream_t stream) {
  const float* in = (const float*)d_in[0];
  float* out = (float*)d_out;

  const size_t table_bytes = 3 * 512 * sizeof(float);  // 6 KB
  if (ws_size >= table_bytes) {
    float* radT = (float*)d_ws;
    float* cT = radT + 512;
    float* sT = cT + 512;
    table_kernel<<<dim3(2), dim3(256), 0, stream>>>(radT, cT, sT);
    resample_kernel<<<dim3((NPIX / 256) * NG), dim3(256), 0, stream>>>(
        in, out, radT, cT, sT);
  } else {
    logpolar_mono<<<dim3(NPIX / 256), dim3(256), 0, stream>>>(in, out);
  }
}

// Round 8
// 63.627 us; speedup vs baseline: 1.2458x; 1.2458x over previous
//
#include <hip/hip_runtime.h>
#include <math.h>

// LogPolar resample: data (32,3,512,512) f32 -> out (32,3,512,512) f32.
//
// R8 = R6 (best: 62.9us) + block footprint remap 1theta x 256j -> 4theta x 64j.
//  1) table_kernel (2 blocks): rad=exp(j*max_r/512) (j-only), cos/sin(ang(i))
//     (i-only) -> 3*512 floats in d_ws. Correctly-rounded f32 via f64 libm,
//     bit-identical to the validated chain (trunc/mask decisions are
//     discontinuous -> must match np reference exactly).
//  2) resample_kernel (32768 blocks, PPB=3, NG=32): X,Y from tables with
//     native f32 ops (bit-identical); f32 weights (~1e-7 error << 6.5e-2).
//     BLOCK TILE (new): 4 waves of a block = 4 ADJACENT theta rays over the
//     SAME 64-j radius window (adjacent rays are rad*0.0123 px apart -> the
//     4 waves' corner gathers share 64B lines while co-resident in L1).
//     R6 layout had 4 waves = 4 disjoint radial bands (zero line sharing).
//     Store coalescing unchanged: each wave writes 64 contiguous floats.
//     g = blockIdx&31 (XCD partition: 12 planes/XCD); pixblock = blockIdx>>5,
//     same-CU blocks step pixblock by 8 on the SAME plane (L1 plane affinity).
//
// Ladder: R2 210 -> R4 164 -> R6 98.7 -> R7 131.8 (profiled; PPB=1 REGRESSED:
// wave axis exhausted at occ ~75%, map-VALU doubled). R5 anti-lesson: float4
// gather merge regressed. Current theory: TA distinct-line lookups (~19M,
// ~31us) sit on top of the 23us HBM floor -> attack line sharing.

#define HW (512 * 512)
#define NPIX (512 * 512)
#define PLANES 96
#define PPB 3   // planes per resample block
#define NG 32   // plane groups (PLANES/PPB)

// ---------------- table kernel: 512 entries of rad/cos/sin ----------------
__global__ __launch_bounds__(256) void table_kernel(float* __restrict__ radT,
                                                    float* __restrict__ cT,
                                                    float* __restrict__ sT) {
  const int t = blockIdx.x * 256 + threadIdx.x;  // 0..511

  // max_r = log(sqrt(512^2+512^2)/2 * 700), all in f32 steps (CR via f64)
  const float sq_f = (float)sqrt(524288.0);             // f32 sqrt (CR)
  const float half_f = sq_f * 0.5f;                     // exact
  const float prod_f = (float)((double)half_f * 700.0); // f32 mul emulated
  const float maxr_f = (float)log((double)prod_f);      // f32 log (CR)

  // rad = exp(t * max_r / 512) in f32 steps
  const float t1 = (float)((double)(float)t * (double)maxr_f); // f32 mul
  const float tt = t1 * (1.0f / 512.0f);                       // exact (pow2)
  radT[t] = (float)exp((double)tt);                            // f32 exp (CR)

  // ang = t * 2.0 * f32(pi) / 512 in f32 steps
  const float two_i = (float)(2 * t);  // exact
  const float ang1 = (float)((double)two_i * (double)(float)M_PI); // f32 mul
  const float ang = ang1 * (1.0f / 512.0f);                        // exact
  cT[t] = (float)cos((double)ang);  // f32 cos (CR)
  sT[t] = (float)sin((double)ang);  // f32 sin (CR)
}

// ---------------- resample kernel ----------------
__global__ __launch_bounds__(256) void resample_kernel(
    const float* __restrict__ in, float* __restrict__ out,
    const float* __restrict__ radT, const float* __restrict__ cT,
    const float* __restrict__ sT) {
  const int g = blockIdx.x & (NG - 1);   // plane group; g&7 = XCD partition
  const int pixblock = blockIdx.x >> 5;  // 0..1023 (tile index)

  // 4theta x 64j tile: tiles laid out 128 (theta-groups) x 8 (j-windows)
  const int i = ((pixblock >> 3) << 2) + ((int)threadIdx.x >> 6);  // theta
  const int j = ((pixblock & 7) << 6) + ((int)threadIdx.x & 63);   // radius
  const int pix = i * 512 + j;

  const float rad = radT[j];
  const float c = cT[i];
  const float s = sT[i];

  // Native f32 ops == "exact in f64, round once" -> X,Y bit-identical to the
  // validated chain; all trunc/mask decisions follow from X,Y alone.
  const float X = __fadd_rn(256.0f, __fmul_rn(rad, c));
  const float Y = __fsub_rn(256.0f, __fmul_rn(rad, s));

  const int p0 = g * PPB;
  float* op = out + (size_t)p0 * HW + pix;

  const bool inb = (X >= 0.0f) && (X < 512.0f) && (Y >= 0.0f) && (Y < 512.0f);
  if (!inb) {
#pragma unroll
    for (int p = 0; p < PPB; ++p) {
      __builtin_nontemporal_store(0.0f, op);
      op += HW;
    }
    return;
  }

  // corner indices (decisions from bit-exact X,Y) + f32 weights
  const int yd = (int)Y;  // trunc == floor for Y in [0,512)
  const int xd = (int)X;
  const int yu = min(yd + 1, 511);
  const int xu = min(xd + 1, 511);
  const float fyd = (Y - (float)yd) * (Y - (float)yd);
  const float fyu = (Y - (float)yu) * (Y - (float)yu);
  const float fxd = (X - (float)xd) * (X - (float)xd);
  const float fxu = (X - (float)xu) * (X - (float)xu);
  const float dd = fyd + fxd;
  const float du = fyd + fxu;
  const float ud = fyu + fxd;
  const float uu = fyu + fxu;
  const float inv = 1.0f / (dd + du + ud + uu);
  const float wdd = dd * inv;
  const float wdu = du * inv;
  const float wud = ud * inv;
  const float wuu = uu * inv;

  const int i00 = yd * 512 + xd;
  const int i01 = yd * 512 + xu;
  const int i10 = yu * 512 + xd;
  const int i11 = yu * 512 + xu;

  const float* ip = in + (size_t)p0 * HW;
#pragma unroll
  for (int p = 0; p < PPB; ++p) {
    const float v =
        wdd * ip[i00] + wdu * ip[i01] + wud * ip[i10] + wuu * ip[i11];
    __builtin_nontemporal_store(v, op);
    ip += HW;
    op += HW;
  }
}

// ---------------- fallback: proven R2 monolithic kernel ----------------
__global__ __launch_bounds__(256) void logpolar_mono(
    const float* __restrict__ in, float* __restrict__ out) {
  const int pix = blockIdx.x * 256 + threadIdx.x;
  const int i = pix >> 9;
  const int j = pix & 511;

  const float sq_f = (float)sqrt(524288.0);
  const float half_f = sq_f * 0.5f;
  const float prod_f = (float)((double)half_f * 700.0);
  const float maxr_f = (float)log((double)prod_f);
  const float t1 = (float)((double)(float)j * (double)maxr_f);
  const float t = t1 * (1.0f / 512.0f);
  const float rad_f = (float)exp((double)t);
  const float two_i = (float)(2 * i);
  const float ang1 = (float)((double)two_i * (double)(float)M_PI);
  const float ang = ang1 * (1.0f / 512.0f);
  const float c_f = (float)cos((double)ang);
  const float s_f = (float)sin((double)ang);
  const float X0 = (float)((double)rad_f * (double)c_f);
  const float Y0 = (float)((double)rad_f * (double)s_f);
  const float X = (float)(256.0 + (double)X0);
  const float Y = (float)(256.0 - (double)Y0);

  const bool inb = (X >= 0.0f) && (X < 512.0f) && (Y >= 0.0f) && (Y < 512.0f);

  float wdd = 0.f, wdu = 0.f, wud = 0.f, wuu = 0.f;
  int idd = 0, idu = 0, iud = 0, iuu = 0;
  if (inb) {
    const int yd = (int)Y;
    const int xd = (int)X;
    const int yu = min(yd + 1, 511);
    const int xu = min(xd + 1, 511);
    const double Xd = (double)X, Yd = (double)Y;
    const double dyd = (Yd - (double)yd) * (Yd - (double)yd);
    const double dyu = (Yd - (double)yu) * (Yd - (double)yu);
    const double dxd = (Xd - (double)xd) * (Xd - (double)xd);
    const double dxu = (Xd - (double)xu) * (Xd - (double)xu);
    const double dd = dyd + dxd;
    const double du = dyd + dxu;
    const double ud = dyu + dxd;
    const double uu = dyu + dxu;
    const double inv = 1.0 / (dd + du + ud + uu);
    wdd = (float)(dd * inv);
    wdu = (float)(du * inv);
    wud = (float)(ud * inv);
    wuu = (float)(uu * inv);
    idd = yd * 512 + xd;
    idu = yd * 512 + xu;
    iud = yu * 512 + xd;
    iuu = yu * 512 + xu;
  }

  const float* __restrict__ ip = in;
  float* __restrict__ op = out + pix;
#pragma unroll 4
  for (int p = 0; p < PLANES; ++p) {
    float v = 0.0f;
    if (inb) {
      v = wdd * ip[idd] + wdu * ip[idu] + wud * ip[iud] + wuu * ip[iuu];
    }
    *op = v;
    ip += HW;
    op += HW;
  }
}

extern "C" void kernel_launch(void* const* d_in, const int* in_sizes, int n_in,
                              void* d_out, int out_size, void* d_ws,
                              size_t ws_size, hipStream_t stream) {
  const float* in = (const float*)d_in[0];
  float* out = (float*)d_out;

  const size_t table_bytes = 3 * 512 * sizeof(float);  // 6 KB
  if (ws_size >= table_bytes) {
    float* radT = (float*)d_ws;
    float* cT = radT + 512;
    float* sT = cT + 512;
    table_kernel<<<dim3(2), dim3(256), 0, stream>>>(radT, cT, sT);
    resample_kernel<<<dim3((NPIX / 256) * NG), dim3(256), 0, stream>>>(
        in, out, radT, cT, sT);
  } else {
    logpolar_mono<<<dim3(NPIX / 256), dim3(256), 0, stream>>>(in, out);
  }
}